// Round 1
// baseline (335.824 us; speedup 1.0000x reference)
//
#include <hip/hip_runtime.h>
#include <hip/hip_bf16.h>
#include <stdint.h>

#define MM 4
#define NN 65536
#define DD 256
#define KTOT 1024

typedef uint32_t u32;
typedef __attribute__((ext_vector_type(4))) float f32x4;
typedef __attribute__((ext_vector_type(4))) u32 u32x4;
typedef __attribute__((ext_vector_type(2))) u32 u32x2;
typedef __attribute__((ext_vector_type(8))) short s16x8;

__device__ inline unsigned short f2bf(float f) {
    // round-to-nearest-even f32 -> bf16
    union { float f; u32 u; } v; v.f = f;
    u32 u = v.u;
    u32 r = (u + 0x7fffu + ((u >> 16) & 1u)) >> 16;
    return (unsigned short)r;
}

// Build Wbt[c][k] (bf16): Wbt[(i*256+e)*1024 + j*256+f] = (i!=j) ? bf16(W[i,j,e,f]) : 0
__global__ void prep_w(const float* __restrict__ W, unsigned short* __restrict__ Wbt) {
    int t = blockIdx.x * blockDim.x + threadIdx.x;   // 256K threads
    int o = t * 4;                                   // element offset in Wbt
    int c  = o >> 10;
    int kk = o & 1023;
    int i = c >> 8, e = c & 255;
    int j = kk >> 8, f = kk & 255;
    f32x4 w = *(const f32x4*)(W + ((size_t)((i * 4 + j) * 256 + e) << 8) + f);
    u32 p0 = (u32)f2bf(w[0]) | ((u32)f2bf(w[1]) << 16);
    u32 p1 = (u32)f2bf(w[2]) | ((u32)f2bf(w[3]) << 16);
    if (i == j) { p0 = 0u; p1 = 0u; }
    u32x2 pr = {p0, p1};
    *(u32x2*)(Wbt + o) = pr;
}

// bsum[i*256+e] = sum_{j != i} b[i,j,e]
__global__ void prep_b(const float* __restrict__ b, float* __restrict__ bsum) {
    int c = blockIdx.x * blockDim.x + threadIdx.x;   // 1024
    if (c >= 1024) return;
    int i = c >> 8, e = c & 255;
    float s = 0.0f;
    #pragma unroll
    for (int j = 0; j < 4; ++j)
        if (j != i) s += b[((i * 4 + j) << 8) + e];
    bsum[c] = s;
}

// 128x128 output tile, BK=64, 256 threads = 4 waves (2x2), 16x16x32 bf16 MFMA.
__global__ __launch_bounds__(256, 2) void fusion_gemm(
    const float* __restrict__ x, const unsigned short* __restrict__ Wbt,
    const float* __restrict__ bsum, float* __restrict__ out) {
    __shared__ unsigned short Alds[128 * 64];   // [row][k] bf16, XOR-swizzled
    __shared__ unsigned short Blds[128 * 64];   // [col][k] bf16, XOR-swizzled

    const int tid = threadIdx.x;
    const int bid = blockIdx.x;
    const int ytile = bid & 7;      // col block fastest -> A row-panel shared in L3
    const int xtile = bid >> 3;
    const int i = ytile >> 1;       // output modality
    const int n0 = xtile * 128;
    const int col0 = ytile * 128;   // global GEMM col base

    const int lane = tid & 63;
    const int wid = tid >> 6;
    const int wm = wid >> 1;        // 0..1
    const int wn = wid & 1;         // 0..1

    f32x4 acc[4][4];
    #pragma unroll
    for (int a = 0; a < 4; ++a)
        #pragma unroll
        for (int b2 = 0; b2 < 4; ++b2)
            acc[a][b2] = (f32x4){0.f, 0.f, 0.f, 0.f};

    const int sr = tid >> 1;        // staging row (A) / col (B), 0..127
    const int sh = tid & 1;         // which 32-elem half of the 64-elem row

    char* Ab = (char*)Alds;
    char* Bb = (char*)Blds;

    for (int jj = 0; jj < 3; ++jj) {
        const int j = jj + (jj >= i);               // skip j == i
        const float* xj = x + (size_t)j * ((size_t)NN * DD);
        for (int kk = 0; kk < 256; kk += 64) {
            // ---- global loads to regs ----
            const float* asrc = xj + (size_t)(n0 + sr) * DD + kk + sh * 32;
            f32x4 av[8];
            #pragma unroll
            for (int q = 0; q < 8; ++q) av[q] = *(const f32x4*)(asrc + q * 4);
            const unsigned short* bsrc = Wbt + (size_t)(col0 + sr) * KTOT + (j * 256 + kk) + sh * 32;
            u32x4 bv[4];
            #pragma unroll
            for (int q = 0; q < 4; ++q) bv[q] = *(const u32x4*)((const char*)bsrc + q * 16);

            __syncthreads();        // previous compute done reading LDS

            // ---- A: convert f32->bf16, swizzled ds_write ----
            #pragma unroll
            for (int q = 0; q < 4; ++q) {
                f32x4 v0 = av[2 * q], v1 = av[2 * q + 1];
                u32x4 p;
                p[0] = (u32)f2bf(v0[0]) | ((u32)f2bf(v0[1]) << 16);
                p[1] = (u32)f2bf(v0[2]) | ((u32)f2bf(v0[3]) << 16);
                p[2] = (u32)f2bf(v1[0]) | ((u32)f2bf(v1[1]) << 16);
                p[3] = (u32)f2bf(v1[2]) | ((u32)f2bf(v1[3]) << 16);
                u32 o = (u32)(sr * 128 + sh * 64 + q * 16);
                o ^= (u32)((sr & 7) << 4);
                *(u32x4*)(Ab + o) = p;
            }
            // ---- B: swizzled ds_write ----
            #pragma unroll
            for (int q = 0; q < 4; ++q) {
                u32 o = (u32)(sr * 128 + sh * 64 + q * 16);
                o ^= (u32)((sr & 7) << 4);
                *(u32x4*)(Bb + o) = bv[q];
            }
            __syncthreads();        // tile ready

            // ---- MFMA ----
            #pragma unroll
            for (int kh = 0; kh < 2; ++kh) {
                s16x8 af[4], bfr[4];
                #pragma unroll
                for (int fm = 0; fm < 4; ++fm) {
                    int row = wm * 64 + fm * 16 + (lane & 15);
                    u32 o = (u32)(row * 128 + kh * 64 + (lane >> 4) * 16);
                    o ^= (u32)((row & 7) << 4);
                    af[fm] = *(const s16x8*)(Ab + o);
                }
                #pragma unroll
                for (int fn = 0; fn < 4; ++fn) {
                    int col = wn * 64 + fn * 16 + (lane & 15);
                    u32 o = (u32)(col * 128 + kh * 64 + (lane >> 4) * 16);
                    o ^= (u32)((col & 7) << 4);
                    bfr[fn] = *(const s16x8*)(Bb + o);
                }
                #pragma unroll
                for (int fm = 0; fm < 4; ++fm)
                    #pragma unroll
                    for (int fn = 0; fn < 4; ++fn)
                        acc[fm][fn] = __builtin_amdgcn_mfma_f32_16x16x32_bf16(
                            af[fm], bfr[fn], acc[fm][fn], 0, 0, 0);
            }
        }
    }

    // ---- epilogue: out = acc + x[i] + bsum ----
    const int r0 = (lane >> 4) * 4;
    const int cl = lane & 15;
    #pragma unroll
    for (int fm = 0; fm < 4; ++fm) {
        #pragma unroll
        for (int fn = 0; fn < 4; ++fn) {
            int col_l = wn * 64 + fn * 16 + cl;
            int cglob = col0 + col_l;
            float bs = bsum[cglob];
            int e = cglob & 255;
            #pragma unroll
            for (int r = 0; r < 4; ++r) {
                int row_l = wm * 64 + fm * 16 + r0 + r;
                int n = n0 + row_l;
                size_t oidx = ((size_t)i * NN + n) * DD + e;
                out[oidx] = acc[fm][fn][r] + x[oidx] + bs;
            }
        }
    }
}

extern "C" void kernel_launch(void* const* d_in, const int* in_sizes, int n_in,
                              void* d_out, int out_size, void* d_ws, size_t ws_size,
                              hipStream_t stream) {
    const float* x = (const float*)d_in[0];
    const float* W = (const float*)d_in[1];
    const float* b = (const float*)d_in[2];
    float* out = (float*)d_out;

    unsigned short* Wbt = (unsigned short*)d_ws;                       // 2 MB bf16
    float* bsum = (float*)((char*)d_ws + (size_t)2 * 1024 * 1024);     // 4 KB f32

    hipLaunchKernelGGL(prep_w, dim3(1024), dim3(256), 0, stream, W, Wbt);
    hipLaunchKernelGGL(prep_b, dim3(4), dim3(256), 0, stream, b, bsum);
    hipLaunchKernelGGL(fusion_gemm, dim3(4096), dim3(256), 0, stream, x, Wbt, bsum, out);
}

// Round 2
// 319.531 us; speedup vs baseline: 1.0510x; 1.0510x over previous
//
#include <hip/hip_runtime.h>
#include <hip/hip_bf16.h>
#include <stdint.h>

#define NN 65536
#define DD 256

typedef uint32_t u32;
typedef __attribute__((ext_vector_type(4))) float f32x4;
typedef __attribute__((ext_vector_type(4))) u32 u32x4;
typedef __attribute__((ext_vector_type(2))) u32 u32x2;
typedef __attribute__((ext_vector_type(8))) short s16x8;

__device__ inline unsigned short f2bf(float f) {
    union { float f; u32 u; } v; v.f = f;
    u32 u = v.u;
    return (unsigned short)((u + 0x7fffu + ((u >> 16) & 1u)) >> 16);
}

__device__ inline void gl2lds16(const void* g, void* s) {
    __builtin_amdgcn_global_load_lds(
        (const __attribute__((address_space(1))) void*)g,
        (__attribute__((address_space(3))) void*)s, 16, 0, 0);
}

// Build the pre-swizzled B image: for each (ct, j, kk) a 16 KB tile that is the
// exact byte image of the GEMM's swizzled B LDS buffer, so staging is 4 straight
// global_load_lds_dwordx4 per thread (linear LDS dest, swizzle baked into source).
// Image element p (within tile): col = p>>6, r2e = p&63, kl = r2e ^ ((col&7)<<3).
// Value = (i==j) ? 0 : bf16(W[i,j,e,f]) with c=ct*128+col, i=c>>8, e=c&255, f=kk*64+kl.
__global__ void prep_w(const float* __restrict__ W, unsigned short* __restrict__ Wimg) {
    int t = blockIdx.x * blockDim.x + threadIdx.x;   // 262144 threads
    int E = t * 4;                                   // element index in image
    int tile = E >> 13;                              // 8192 elems per 16KB tile
    int pin = E & 8191;
    int col = pin >> 6;
    int r2e = pin & 63;                              // aligned 4
    int ct = tile >> 4;
    int j = (tile >> 2) & 3;
    int kk = tile & 3;
    int kl = r2e ^ ((col & 7) << 3);                 // aligned 4 (XOR hits bits 3..5)
    int c = ct * 128 + col;
    int i = c >> 8, e = c & 255;
    int f = kk * 64 + kl;
    f32x4 w = *(const f32x4*)(W + ((size_t)((i * 4 + j) * 256 + e) << 8) + f);
    u32 p0 = (u32)f2bf(w[0]) | ((u32)f2bf(w[1]) << 16);
    u32 p1 = (u32)f2bf(w[2]) | ((u32)f2bf(w[3]) << 16);
    if (i == j) { p0 = 0u; p1 = 0u; }
    u32x2 pr = {p0, p1};
    *(u32x2*)(Wimg + E) = pr;
}

// bsum[i*256+e] = sum_{j != i} b[i,j,e]
__global__ void prep_b(const float* __restrict__ b, float* __restrict__ bsum) {
    int c = blockIdx.x * blockDim.x + threadIdx.x;
    if (c >= 1024) return;
    int i = c >> 8, e = c & 255;
    float s = 0.0f;
    #pragma unroll
    for (int j = 0; j < 4; ++j)
        if (j != i) s += b[((i * 4 + j) << 8) + e];
    bsum[c] = s;
}

// 128x128 tile, BK=64, 4 waves (2x2), 16x16x32 bf16 MFMA.
// 2-phase pipeline: prefetch A(t+1)->regs and B(t+1)->LDS (global_load_lds, dbuf)
// before MFMA(t); barrier drain at next iter overlaps with MFMA.
__global__ __launch_bounds__(256, 2) void fusion_gemm(
    const float* __restrict__ x, const unsigned short* __restrict__ Wimg,
    const float* __restrict__ bsum, float* __restrict__ out) {
    __shared__ __attribute__((aligned(16))) unsigned short Alds[128 * 64];
    __shared__ __attribute__((aligned(16))) unsigned short Blds[2][128 * 64];

    const int tid = threadIdx.x;
    const int bid = blockIdx.x;
    // XCD-locality swizzle: all 8 col-tiles of a row-panel on the same XCD,
    // temporally adjacent (ct innermost per XCD).
    const int xcd = bid & 7;
    const int slot = bid >> 3;
    const int ct = slot & 7;
    const int rhi = slot >> 3;                 // [0,64)
    const int rtile = rhi * 8 + xcd;           // [0,512)
    const int n0 = rtile * 128;
    const int col0 = ct * 128;
    const int i = ct >> 1;                     // output modality

    const int lane = tid & 63;
    const int wid = tid >> 6;
    const int wm = wid >> 1;
    const int wn = wid & 1;

    f32x4 acc[4][4];
    #pragma unroll
    for (int a = 0; a < 4; ++a)
        #pragma unroll
        for (int b2 = 0; b2 < 4; ++b2)
            acc[a][b2] = (f32x4){0.f, 0.f, 0.f, 0.f};

    const int sr = tid >> 1;
    const int sh = tid & 1;
    char* Ab = (char*)Alds;
    const char* WimgB = (const char*)Wimg;

    f32x4 av[8];

    // ---- prologue: prefetch t=0 ----
    {
        int j0 = (i == 0) ? 1 : 0;
        const float* asrc = x + (size_t)j0 * ((size_t)NN * DD) + (size_t)(n0 + sr) * DD + sh * 32;
        #pragma unroll
        for (int q = 0; q < 8; ++q) av[q] = *(const f32x4*)(asrc + q * 4);
        const char* base = WimgB + (((size_t)(ct * 4 + j0) * 4 + 0) << 14) + wid * 1024 + lane * 16;
        char* lb = (char*)Blds[0] + wid * 1024;
        #pragma unroll
        for (int q = 0; q < 4; ++q) gl2lds16(base + q * 4096, lb + q * 4096);
    }

    for (int t = 0; t < 12; ++t) {
        __syncthreads();   // (1) consumers of t-1 done; drains A(t)/B(t) prefetch (covered by MFMA(t-1))

        // ---- A(t): convert + swizzled ds_write ----
        #pragma unroll
        for (int q = 0; q < 4; ++q) {
            f32x4 v0 = av[2 * q], v1 = av[2 * q + 1];
            u32x4 p;
            p[0] = (u32)f2bf(v0[0]) | ((u32)f2bf(v0[1]) << 16);
            p[1] = (u32)f2bf(v0[2]) | ((u32)f2bf(v0[3]) << 16);
            p[2] = (u32)f2bf(v1[0]) | ((u32)f2bf(v1[1]) << 16);
            p[3] = (u32)f2bf(v1[2]) | ((u32)f2bf(v1[3]) << 16);
            u32 o = (u32)(sr * 128 + sh * 64 + q * 16);
            o ^= (u32)((sr & 7) << 4);
            *(u32x4*)(Ab + o) = p;
        }
        __syncthreads();   // (2) lgkm drain only (cheap)

        // ---- prefetch t+1 (overlaps with MFMA(t)) ----
        if (t < 11) {
            int tn = t + 1;
            int jjn = tn >> 2;
            int jn = jjn + (jjn >= i);
            int kkn = tn & 3;
            const char* base = WimgB + (((size_t)(ct * 4 + jn) * 4 + kkn) << 14) + wid * 1024 + lane * 16;
            char* lb = (char*)Blds[tn & 1] + wid * 1024;
            #pragma unroll
            for (int q = 0; q < 4; ++q) gl2lds16(base + q * 4096, lb + q * 4096);
            const float* asrc = x + (size_t)jn * ((size_t)NN * DD) + (size_t)(n0 + sr) * DD + kkn * 64 + sh * 32;
            #pragma unroll
            for (int q = 0; q < 8; ++q) av[q] = *(const f32x4*)(asrc + q * 4);
        }

        // ---- MFMA(t) ----
        const char* Bb = (const char*)Blds[t & 1];
        #pragma unroll
        for (int kh = 0; kh < 2; ++kh) {
            s16x8 af[4], bfr[4];
            #pragma unroll
            for (int fm = 0; fm < 4; ++fm) {
                int row = wm * 64 + fm * 16 + (lane & 15);
                u32 o = (u32)(row * 128 + kh * 64 + (lane >> 4) * 16);
                o ^= (u32)((row & 7) << 4);
                af[fm] = *(const s16x8*)(Ab + o);
            }
            #pragma unroll
            for (int fn = 0; fn < 4; ++fn) {
                int col = wn * 64 + fn * 16 + (lane & 15);
                u32 o = (u32)(col * 128 + kh * 64 + (lane >> 4) * 16);
                o ^= (u32)((col & 7) << 4);
                bfr[fn] = *(const s16x8*)(Bb + o);
            }
            #pragma unroll
            for (int fm = 0; fm < 4; ++fm)
                #pragma unroll
                for (int fn = 0; fn < 4; ++fn)
                    acc[fm][fn] = __builtin_amdgcn_mfma_f32_16x16x32_bf16(
                        af[fm], bfr[fn], acc[fm][fn], 0, 0, 0);
        }
    }

    // ---- epilogue: out = acc + x[i] + bsum (x re-read is an L2 hit: part of panel) ----
    const int r0 = (lane >> 4) * 4;
    const int cl = lane & 15;
    #pragma unroll
    for (int fm = 0; fm < 4; ++fm) {
        #pragma unroll
        for (int fn = 0; fn < 4; ++fn) {
            int col_l = wn * 64 + fn * 16 + cl;
            int cglob = col0 + col_l;
            float bs = bsum[cglob];
            int e = cglob & 255;
            #pragma unroll
            for (int r = 0; r < 4; ++r) {
                int row_l = wm * 64 + fm * 16 + r0 + r;
                int n = n0 + row_l;
                size_t oidx = ((size_t)i * NN + n) * DD + e;
                out[oidx] = acc[fm][fn][r] + x[oidx] + bs;
            }
        }
    }
}

extern "C" void kernel_launch(void* const* d_in, const int* in_sizes, int n_in,
                              void* d_out, int out_size, void* d_ws, size_t ws_size,
                              hipStream_t stream) {
    const float* x = (const float*)d_in[0];
    const float* W = (const float*)d_in[1];
    const float* b = (const float*)d_in[2];
    float* out = (float*)d_out;

    unsigned short* Wimg = (unsigned short*)d_ws;                      // 2 MB bf16 (swizzled image)
    float* bsum = (float*)((char*)d_ws + (size_t)2 * 1024 * 1024);     // 4 KB f32

    hipLaunchKernelGGL(prep_w, dim3(1024), dim3(256), 0, stream, W, Wimg);
    hipLaunchKernelGGL(prep_b, dim3(4), dim3(256), 0, stream, b, bsum);
    hipLaunchKernelGGL(fusion_gemm, dim3(4096), dim3(256), 0, stream, x, Wimg, bsum, out);
}

// Round 3
// 314.294 us; speedup vs baseline: 1.0685x; 1.0167x over previous
//
#include <hip/hip_runtime.h>
#include <hip/hip_bf16.h>
#include <stdint.h>

#define NN 65536
#define DD 256

typedef uint32_t u32;
typedef __attribute__((ext_vector_type(4))) float f32x4;
typedef __attribute__((ext_vector_type(4))) u32 u32x4;
typedef __attribute__((ext_vector_type(2))) u32 u32x2;
typedef __attribute__((ext_vector_type(8))) short s16x8;

__device__ inline unsigned short f2bf(float f) {
    union { float f; u32 u; } v; v.f = f;
    u32 u = v.u;
    return (unsigned short)((u + 0x7fffu + ((u >> 16) & 1u)) >> 16);
}

__device__ inline void gl2lds16(const void* g, void* s) {
    __builtin_amdgcn_global_load_lds(
        (const __attribute__((address_space(1))) void*)g,
        (__attribute__((address_space(3))) void*)s, 16, 0, 0);
}

// ---- Pre-swizzled B image (verified in R2). Tile (ct,j,kk) is the byte image of
// the swizzled B LDS buffer: element p: col=p>>6, r2e=p&63, kl=r2e^((col&7)<<3).
__global__ void prep_w(const float* __restrict__ W, unsigned short* __restrict__ Wimg) {
    int t = blockIdx.x * blockDim.x + threadIdx.x;   // 262144 threads
    int E = t * 4;
    int tile = E >> 13;
    int pin = E & 8191;
    int col = pin >> 6;
    int r2e = pin & 63;
    int ct = tile >> 4;
    int j = (tile >> 2) & 3;
    int kk = tile & 3;
    int kl = r2e ^ ((col & 7) << 3);
    int c = ct * 128 + col;
    int i = c >> 8, e = c & 255;
    int f = kk * 64 + kl;
    f32x4 w = *(const f32x4*)(W + ((size_t)((i * 4 + j) * 256 + e) << 8) + f);
    u32 p0 = (u32)f2bf(w[0]) | ((u32)f2bf(w[1]) << 16);
    u32 p1 = (u32)f2bf(w[2]) | ((u32)f2bf(w[3]) << 16);
    if (i == j) { p0 = 0u; p1 = 0u; }
    u32x2 pr = {p0, p1};
    *(u32x2*)(Wimg + E) = pr;
}

// ---- Pre-swizzled A image: same 16KB tile format, tile index (j*512+rtile)*4+kk,
// within-tile: row=p>>6, r2e=p&63, kl=r2e^((row&7)<<3), value=bf16(x[j][rtile*128+row][kk*64+kl]).
__global__ void prep_x(const float* __restrict__ x, unsigned short* __restrict__ Ximg) {
    int t = blockIdx.x * blockDim.x + threadIdx.x;   // 16M threads
    int E = t * 4;
    int tile = E >> 13;          // (j*512 + rt)*4 + kk
    int pin = E & 8191;
    int row = pin >> 6;
    int r2e = pin & 63;
    int kk = tile & 3;
    int rt = (tile >> 2) & 511;
    int j = tile >> 11;
    int kl = r2e ^ ((row & 7) << 3);
    int n = rt * 128 + row;
    int f = kk * 64 + kl;
    f32x4 v = *(const f32x4*)(x + ((size_t)j * NN + n) * DD + f);
    u32 p0 = (u32)f2bf(v[0]) | ((u32)f2bf(v[1]) << 16);
    u32 p1 = (u32)f2bf(v[2]) | ((u32)f2bf(v[3]) << 16);
    u32x2 pr = {p0, p1};
    *(u32x2*)(Ximg + E) = pr;
}

// bsum[i*256+e] = sum_{j != i} b[i,j,e]
__global__ void prep_b(const float* __restrict__ b, float* __restrict__ bsum) {
    int c = blockIdx.x * blockDim.x + threadIdx.x;
    if (c >= 1024) return;
    int i = c >> 8, e = c & 255;
    float s = 0.0f;
    #pragma unroll
    for (int j = 0; j < 4; ++j)
        if (j != i) s += b[((i * 4 + j) << 8) + e];
    bsum[c] = s;
}

// ---- Main GEMM: 128x128 tile, BK=64, 4 waves (2x2). Both A and B staged by
// global_load_lds width-16 from pre-swizzled images, double-buffered, 2-phase.
__global__ __launch_bounds__(256, 2) void fusion_gemm2(
    const float* __restrict__ x, const unsigned short* __restrict__ Wimg,
    const unsigned short* __restrict__ Ximg, const float* __restrict__ bsum,
    float* __restrict__ out) {
    __shared__ __attribute__((aligned(16))) unsigned short Alds[2][8192];
    __shared__ __attribute__((aligned(16))) unsigned short Blds[2][8192];

    const int tid = threadIdx.x;
    const int bid = blockIdx.x;
    const int xcd = bid & 7;
    const int slot = bid >> 3;
    const int ct = slot & 7;
    const int rhi = slot >> 3;
    const int rtile = rhi * 8 + xcd;
    const int n0 = rtile * 128;
    const int col0 = ct * 128;
    const int i = ct >> 1;

    const int lane = tid & 63;
    const int wid = tid >> 6;
    const int wm = wid >> 1;
    const int wn = wid & 1;

    f32x4 acc[4][4];
    #pragma unroll
    for (int a = 0; a < 4; ++a)
        #pragma unroll
        for (int b2 = 0; b2 < 4; ++b2)
            acc[a][b2] = (f32x4){0.f, 0.f, 0.f, 0.f};

    const char* WimgB = (const char*)Wimg;
    const char* XimgB = (const char*)Ximg;
    const u32 toff = (u32)(wid * 1024 + lane * 16);  // per-lane global sub-offset
    const u32 loff = (u32)(wid * 1024);              // wave-uniform LDS sub-offset

    // stage K-step t into buffer bsel
#define STAGE(t_, bsel_)                                                            \
    {                                                                               \
        int jj_ = (t_) >> 2;                                                        \
        int j_ = jj_ + (jj_ >= i);                                                  \
        int kk_ = (t_) & 3;                                                         \
        const char* ab_ = XimgB + (((size_t)(j_ * 512 + rtile) * 4 + kk_) << 14) + toff; \
        char* al_ = (char*)Alds[bsel_] + loff;                                      \
        const char* bb_ = WimgB + (((size_t)(ct * 4 + j_) * 4 + kk_) << 14) + toff; \
        char* bl_ = (char*)Blds[bsel_] + loff;                                      \
        _Pragma("unroll")                                                           \
        for (int q = 0; q < 4; ++q) {                                               \
            gl2lds16(ab_ + q * 4096, al_ + q * 4096);                               \
            gl2lds16(bb_ + q * 4096, bl_ + q * 4096);                               \
        }                                                                           \
    }

    STAGE(0, 0);

    for (int t = 0; t < 12; ++t) {
        __syncthreads();            // drains stage(t) (covered by MFMA(t-1))
        if (t < 11) STAGE(t + 1, (t + 1) & 1);

        const char* Ab = (const char*)Alds[t & 1];
        const char* Bb = (const char*)Blds[t & 1];
        #pragma unroll
        for (int kh = 0; kh < 2; ++kh) {
            s16x8 af[4], bfr[4];
            #pragma unroll
            for (int fm = 0; fm < 4; ++fm) {
                int row = wm * 64 + fm * 16 + (lane & 15);
                u32 o = (u32)(row * 128 + kh * 64 + (lane >> 4) * 16);
                o ^= (u32)((row & 7) << 4);
                af[fm] = *(const s16x8*)(Ab + o);
            }
            #pragma unroll
            for (int fn = 0; fn < 4; ++fn) {
                int col = wn * 64 + fn * 16 + (lane & 15);
                u32 o = (u32)(col * 128 + kh * 64 + (lane >> 4) * 16);
                o ^= (u32)((col & 7) << 4);
                bfr[fn] = *(const s16x8*)(Bb + o);
            }
            #pragma unroll
            for (int fm = 0; fm < 4; ++fm)
                #pragma unroll
                for (int fn = 0; fn < 4; ++fn)
                    acc[fm][fn] = __builtin_amdgcn_mfma_f32_16x16x32_bf16(
                        af[fm], bfr[fn], acc[fm][fn], 0, 0, 0);
        }
    }
#undef STAGE

    // ---- epilogue: out = acc + x[i] + bsum ----
    const int r0 = (lane >> 4) * 4;
    const int cl = lane & 15;
    #pragma unroll
    for (int fm = 0; fm < 4; ++fm) {
        #pragma unroll
        for (int fn = 0; fn < 4; ++fn) {
            int col_l = wn * 64 + fn * 16 + cl;
            int cglob = col0 + col_l;
            float bs = bsum[cglob];
            int e = cglob & 255;
            #pragma unroll
            for (int r = 0; r < 4; ++r) {
                int row_l = wm * 64 + fm * 16 + r0 + r;
                int n = n0 + row_l;
                size_t oidx = ((size_t)i * NN + n) * DD + e;
                out[oidx] = acc[fm][fn][r] + x[oidx] + bs;
            }
        }
    }
}

// ---- Fallback (verified R2 kernel) for small ws_size ----
__global__ __launch_bounds__(256, 2) void fusion_gemm_fb(
    const float* __restrict__ x, const unsigned short* __restrict__ Wimg,
    const float* __restrict__ bsum, float* __restrict__ out) {
    __shared__ __attribute__((aligned(16))) unsigned short Alds[128 * 64];
    __shared__ __attribute__((aligned(16))) unsigned short Blds[2][128 * 64];

    const int tid = threadIdx.x;
    const int bid = blockIdx.x;
    const int xcd = bid & 7;
    const int slot = bid >> 3;
    const int ct = slot & 7;
    const int rhi = slot >> 3;
    const int rtile = rhi * 8 + xcd;
    const int n0 = rtile * 128;
    const int col0 = ct * 128;
    const int i = ct >> 1;

    const int lane = tid & 63;
    const int wid = tid >> 6;
    const int wm = wid >> 1;
    const int wn = wid & 1;

    f32x4 acc[4][4];
    #pragma unroll
    for (int a = 0; a < 4; ++a)
        #pragma unroll
        for (int b2 = 0; b2 < 4; ++b2)
            acc[a][b2] = (f32x4){0.f, 0.f, 0.f, 0.f};

    const int sr = tid >> 1;
    const int sh = tid & 1;
    char* Ab = (char*)Alds;
    const char* WimgB = (const char*)Wimg;

    f32x4 av[8];
    {
        int j0 = (i == 0) ? 1 : 0;
        const float* asrc = x + (size_t)j0 * ((size_t)NN * DD) + (size_t)(n0 + sr) * DD + sh * 32;
        #pragma unroll
        for (int q = 0; q < 8; ++q) av[q] = *(const f32x4*)(asrc + q * 4);
        const char* base = WimgB + (((size_t)(ct * 4 + j0) * 4 + 0) << 14) + wid * 1024 + lane * 16;
        char* lb = (char*)Blds[0] + wid * 1024;
        #pragma unroll
        for (int q = 0; q < 4; ++q) gl2lds16(base + q * 4096, lb + q * 4096);
    }

    for (int t = 0; t < 12; ++t) {
        __syncthreads();
        #pragma unroll
        for (int q = 0; q < 4; ++q) {
            f32x4 v0 = av[2 * q], v1 = av[2 * q + 1];
            u32x4 p;
            p[0] = (u32)f2bf(v0[0]) | ((u32)f2bf(v0[1]) << 16);
            p[1] = (u32)f2bf(v0[2]) | ((u32)f2bf(v0[3]) << 16);
            p[2] = (u32)f2bf(v1[0]) | ((u32)f2bf(v1[1]) << 16);
            p[3] = (u32)f2bf(v1[2]) | ((u32)f2bf(v1[3]) << 16);
            u32 o = (u32)(sr * 128 + sh * 64 + q * 16);
            o ^= (u32)((sr & 7) << 4);
            *(u32x4*)(Ab + o) = p;
        }
        __syncthreads();

        if (t < 11) {
            int tn = t + 1;
            int jjn = tn >> 2;
            int jn = jjn + (jjn >= i);
            int kkn = tn & 3;
            const char* base = WimgB + (((size_t)(ct * 4 + jn) * 4 + kkn) << 14) + wid * 1024 + lane * 16;
            char* lb = (char*)Blds[tn & 1] + wid * 1024;
            #pragma unroll
            for (int q = 0; q < 4; ++q) gl2lds16(base + q * 4096, lb + q * 4096);
            const float* asrc = x + (size_t)jn * ((size_t)NN * DD) + (size_t)(n0 + sr) * DD + kkn * 64 + sh * 32;
            #pragma unroll
            for (int q = 0; q < 8; ++q) av[q] = *(const f32x4*)(asrc + q * 4);
        }

        const char* Bb = (const char*)Blds[t & 1];
        #pragma unroll
        for (int kh = 0; kh < 2; ++kh) {
            s16x8 af[4], bfr[4];
            #pragma unroll
            for (int fm = 0; fm < 4; ++fm) {
                int row = wm * 64 + fm * 16 + (lane & 15);
                u32 o = (u32)(row * 128 + kh * 64 + (lane >> 4) * 16);
                o ^= (u32)((row & 7) << 4);
                af[fm] = *(const s16x8*)(Ab + o);
            }
            #pragma unroll
            for (int fn = 0; fn < 4; ++fn) {
                int col = wn * 64 + fn * 16 + (lane & 15);
                u32 o = (u32)(col * 128 + kh * 64 + (lane >> 4) * 16);
                o ^= (u32)((col & 7) << 4);
                bfr[fn] = *(const s16x8*)(Bb + o);
            }
            #pragma unroll
            for (int fm = 0; fm < 4; ++fm)
                #pragma unroll
                for (int fn = 0; fn < 4; ++fn)
                    acc[fm][fn] = __builtin_amdgcn_mfma_f32_16x16x32_bf16(
                        af[fm], bfr[fn], acc[fm][fn], 0, 0, 0);
        }
    }

    const int r0 = (lane >> 4) * 4;
    const int cl = lane & 15;
    #pragma unroll
    for (int fm = 0; fm < 4; ++fm) {
        #pragma unroll
        for (int fn = 0; fn < 4; ++fn) {
            int col_l = wn * 64 + fn * 16 + cl;
            int cglob = col0 + col_l;
            float bs = bsum[cglob];
            int e = cglob & 255;
            #pragma unroll
            for (int r = 0; r < 4; ++r) {
                int row_l = wm * 64 + fm * 16 + r0 + r;
                int n = n0 + row_l;
                size_t oidx = ((size_t)i * NN + n) * DD + e;
                out[oidx] = acc[fm][fn][r] + x[oidx] + bs;
            }
        }
    }
}

extern "C" void kernel_launch(void* const* d_in, const int* in_sizes, int n_in,
                              void* d_out, int out_size, void* d_ws, size_t ws_size,
                              hipStream_t stream) {
    const float* x = (const float*)d_in[0];
    const float* W = (const float*)d_in[1];
    const float* b = (const float*)d_in[2];
    float* out = (float*)d_out;

    unsigned short* Wimg = (unsigned short*)d_ws;                      // 2 MB
    float* bsum = (float*)((char*)d_ws + ((size_t)2 << 20));           // 4 KB
    const size_t ximg_off = (size_t)4 << 20;
    const size_t need = ximg_off + ((size_t)128 << 20);                // 132 MB

    hipLaunchKernelGGL(prep_w, dim3(1024), dim3(256), 0, stream, W, Wimg);
    hipLaunchKernelGGL(prep_b, dim3(4), dim3(256), 0, stream, b, bsum);

    if (ws_size >= need) {
        unsigned short* Ximg = (unsigned short*)((char*)d_ws + ximg_off);  // 128 MB
        hipLaunchKernelGGL(prep_x, dim3(65536), dim3(256), 0, stream, x, Ximg);
        hipLaunchKernelGGL(fusion_gemm2, dim3(4096), dim3(256), 0, stream, x, Wimg, Ximg, bsum, out);
    } else {
        hipLaunchKernelGGL(fusion_gemm_fb, dim3(4096), dim3(256), 0, stream, x, Wimg, bsum, out);
    }
}

// Round 4
// 262.179 us; speedup vs baseline: 1.2809x; 1.1988x over previous
//
#include <hip/hip_runtime.h>
#include <hip/hip_bf16.h>
#include <stdint.h>

#define NN 65536
#define DD 256

typedef uint32_t u32;
typedef __attribute__((ext_vector_type(4))) float f32x4;
typedef __attribute__((ext_vector_type(4))) u32 u32x4;
typedef __attribute__((ext_vector_type(2))) u32 u32x2;
typedef __attribute__((ext_vector_type(8))) short s16x8;

__device__ inline unsigned short f2bf(float f) {
    union { float f; u32 u; } v; v.f = f;
    u32 u = v.u;
    return (unsigned short)((u + 0x7fffu + ((u >> 16) & 1u)) >> 16);
}

__device__ inline void gl2lds16(const void* g, void* s) {
    __builtin_amdgcn_global_load_lds(
        (const __attribute__((address_space(1))) void*)g,
        (__attribute__((address_space(3))) void*)s, 16, 0, 0);
}

// ---- Pre-swizzled B image. Tile (ct,j,kk) = byte image of swizzled B LDS
// buffer [128 cols][64 K] bf16: element p: col=p>>6, r2e=p&63, kl=r2e^((col&7)<<3).
// diag==1: i==j block is bf16 identity (residual folded into GEMM); diag==0: zeros.
__global__ void prep_w(const float* __restrict__ W, unsigned short* __restrict__ Wimg, int diag) {
    int t = blockIdx.x * blockDim.x + threadIdx.x;   // 262144 threads
    int E = t * 4;
    int tile = E >> 13;
    int pin = E & 8191;
    int col = pin >> 6;
    int r2e = pin & 63;
    int ct = tile >> 4;
    int j = (tile >> 2) & 3;
    int kk = tile & 3;
    int kl = r2e ^ ((col & 7) << 3);
    int c = ct * 128 + col;
    int i = c >> 8, e = c & 255;
    int f = kk * 64 + kl;
    u32 p0, p1;
    if (i == j) {
        unsigned short d0 = 0, d1 = 0, d2 = 0, d3 = 0;
        if (diag) {
            d0 = (e == f + 0) ? 0x3F80 : 0;
            d1 = (e == f + 1) ? 0x3F80 : 0;
            d2 = (e == f + 2) ? 0x3F80 : 0;
            d3 = (e == f + 3) ? 0x3F80 : 0;
        }
        p0 = (u32)d0 | ((u32)d1 << 16);
        p1 = (u32)d2 | ((u32)d3 << 16);
    } else {
        f32x4 w = *(const f32x4*)(W + ((size_t)((i * 4 + j) * 256 + e) << 8) + f);
        p0 = (u32)f2bf(w[0]) | ((u32)f2bf(w[1]) << 16);
        p1 = (u32)f2bf(w[2]) | ((u32)f2bf(w[3]) << 16);
    }
    u32x2 pr = {p0, p1};
    *(u32x2*)(Wimg + E) = pr;
}

// ---- Pre-swizzled A image, BM=256 tiles: tile (j*256+rt)*4+kk is the byte image
// of swizzled A LDS [256 rows][64 K] bf16 (32 KB): p: row=p>>6, r2e=p&63,
// kl=r2e^((row&7)<<3), value=bf16(x[j][rt*256+row][kk*64+kl]).
__global__ void prep_x(const float* __restrict__ x, unsigned short* __restrict__ Ximg) {
    int t = blockIdx.x * blockDim.x + threadIdx.x;   // 16.7M threads
    long long E = (long long)t * 4;
    int tile = (int)(E >> 14);
    int pin = (int)(E & 16383);
    int row = pin >> 6;
    int r2e = pin & 63;
    int kk = tile & 3;
    int rt = (tile >> 2) & 255;
    int j = tile >> 10;
    int kl = r2e ^ ((row & 7) << 3);
    int n = rt * 256 + row;
    int f = kk * 64 + kl;
    f32x4 v = *(const f32x4*)(x + ((size_t)j * NN + n) * DD + f);
    u32 p0 = (u32)f2bf(v[0]) | ((u32)f2bf(v[1]) << 16);
    u32 p1 = (u32)f2bf(v[2]) | ((u32)f2bf(v[3]) << 16);
    u32x2 pr = {p0, p1};
    *(u32x2*)(Ximg + E) = pr;
}

// bsum[i*256+e] = sum_{j != i} b[i,j,e]
__global__ void prep_b(const float* __restrict__ b, float* __restrict__ bsum) {
    int c = blockIdx.x * blockDim.x + threadIdx.x;
    if (c >= 1024) return;
    int i = c >> 8, e = c & 255;
    float s = 0.0f;
    #pragma unroll
    for (int j = 0; j < 4; ++j)
        if (j != i) s += b[((i * 4 + j) << 8) + e];
    bsum[c] = s;
}

// ---- Main GEMM: 256x128 tile, BK=64, 8 waves (4x2), K=1024 (identity diagonal).
// 3-buffer LDS, depth-2 prefetch, counted vmcnt(6), one raw s_barrier per K-step.
__global__ __launch_bounds__(512, 1) void fusion_gemm3(
    const unsigned short* __restrict__ Wimg, const unsigned short* __restrict__ Ximg,
    const float* __restrict__ bsum, float* __restrict__ out) {
    // 3 buffers x (A 32KB + B 16KB) = 144 KB
    __shared__ __attribute__((aligned(16))) char lds[3][49152];

    const int tid = threadIdx.x;
    const int bid = blockIdx.x;
    const int xcd = bid & 7;
    const int slot = bid >> 3;          // 0..255
    const int ct = slot & 7;
    const int rhi = slot >> 3;          // 0..31
    const int rtile = rhi * 8 + xcd;    // 0..255
    const int n0 = rtile * 256;
    const int col0 = ct * 128;
    const int i = ct >> 1;
    (void)i;

    const int lane = tid & 63;
    const int wid = tid >> 6;           // 0..7
    const int wm = wid >> 1;            // 0..3  (row 64-block)
    const int wn = wid & 1;             // 0..1  (col 64-block)

    f32x4 acc[4][4];
    #pragma unroll
    for (int a = 0; a < 4; ++a)
        #pragma unroll
        for (int b2 = 0; b2 < 4; ++b2)
            acc[a][b2] = (f32x4){0.f, 0.f, 0.f, 0.f};

    const char* WimgB = (const char*)Wimg;
    const char* XimgB = (const char*)Ximg;
    const u32 goff = (u32)(wid * 1024 + lane * 16);  // per-lane global sub-offset
    const u32 loff = (u32)(wid * 1024);              // wave-uniform LDS sub-offset

#define STAGE(t_, bsel_)                                                              \
    {                                                                                 \
        int j_ = (t_) >> 2;                                                           \
        int kk_ = (t_) & 3;                                                           \
        const char* ab_ = XimgB + (((size_t)(j_ * 256 + rtile) * 4 + kk_) << 15) + goff; \
        char* al_ = lds[bsel_] + loff;                                                \
        _Pragma("unroll")                                                             \
        for (int q = 0; q < 4; ++q) gl2lds16(ab_ + q * 8192, al_ + q * 8192);         \
        const char* bb_ = WimgB + (((size_t)(ct * 4 + j_) * 4 + kk_) << 14) + goff;   \
        char* bl_ = lds[bsel_] + 32768 + loff;                                        \
        _Pragma("unroll")                                                             \
        for (int q = 0; q < 2; ++q) gl2lds16(bb_ + q * 8192, bl_ + q * 8192);         \
    }

    // one K-step of MFMA from buffer bsel
#define MFMA_STEP(bsel_)                                                              \
    {                                                                                 \
        const char* Ab_ = lds[bsel_];                                                 \
        const char* Bb_ = lds[bsel_] + 32768;                                         \
        _Pragma("unroll")                                                             \
        for (int kh = 0; kh < 2; ++kh) {                                              \
            s16x8 af[4], bfr[4];                                                      \
            _Pragma("unroll")                                                         \
            for (int fm = 0; fm < 4; ++fm) {                                          \
                int row = wm * 64 + fm * 16 + (lane & 15);                            \
                u32 o = (u32)(row * 128 + kh * 64 + (lane >> 4) * 16);                \
                o ^= (u32)((row & 7) << 4);                                           \
                af[fm] = *(const s16x8*)(Ab_ + o);                                    \
            }                                                                         \
            _Pragma("unroll")                                                         \
            for (int fn = 0; fn < 4; ++fn) {                                          \
                int col = wn * 64 + fn * 16 + (lane & 15);                            \
                u32 o = (u32)(col * 128 + kh * 64 + (lane >> 4) * 16);                \
                o ^= (u32)((col & 7) << 4);                                           \
                bfr[fn] = *(const s16x8*)(Bb_ + o);                                   \
            }                                                                         \
            _Pragma("unroll")                                                         \
            for (int fm = 0; fm < 4; ++fm)                                            \
                _Pragma("unroll")                                                     \
                for (int fn = 0; fn < 4; ++fn)                                        \
                    acc[fm][fn] = __builtin_amdgcn_mfma_f32_16x16x32_bf16(            \
                        af[fm], bfr[fn], acc[fm][fn], 0, 0, 0);                       \
        }                                                                             \
    }

    STAGE(0, 0);
    STAGE(1, 1);

    #pragma unroll 1
    for (int t = 0; t < 14; ++t) {
        asm volatile("s_waitcnt vmcnt(6)" ::: "memory");   // stage(t) landed; stage(t+1) in flight
        __builtin_amdgcn_s_barrier();
        __builtin_amdgcn_sched_barrier(0);
        STAGE(t + 2, (t + 2) % 3);
        __builtin_amdgcn_s_setprio(1);
        MFMA_STEP(t % 3);
        __builtin_amdgcn_s_setprio(0);
    }
    // t = 14: stage(14)+stage(15) outstanding -> wait to 6 leaves stage(15) in flight
    asm volatile("s_waitcnt vmcnt(6)" ::: "memory");
    __builtin_amdgcn_s_barrier();
    __builtin_amdgcn_sched_barrier(0);
    __builtin_amdgcn_s_setprio(1);
    MFMA_STEP(2);
    __builtin_amdgcn_s_setprio(0);
    // t = 15: drain
    asm volatile("s_waitcnt vmcnt(0)" ::: "memory");
    __builtin_amdgcn_s_barrier();
    __builtin_amdgcn_sched_barrier(0);
    __builtin_amdgcn_s_setprio(1);
    MFMA_STEP(0);
    __builtin_amdgcn_s_setprio(0);

#undef STAGE
#undef MFMA_STEP

    // ---- epilogue: out = acc + bsum (residual folded into GEMM via identity diag) ----
    const int r0 = (lane >> 4) * 4;
    const int cl = lane & 15;
    const int iout = ct >> 1;
    #pragma unroll
    for (int fm = 0; fm < 4; ++fm) {
        #pragma unroll
        for (int fn = 0; fn < 4; ++fn) {
            int col_l = wn * 64 + fn * 16 + cl;
            int cglob = col0 + col_l;
            float bs = bsum[cglob];
            int e = cglob & 255;
            #pragma unroll
            for (int r = 0; r < 4; ++r) {
                int row_l = wm * 64 + fm * 16 + r0 + r;
                int n = n0 + row_l;
                size_t oidx = ((size_t)iout * NN + n) * DD + e;
                out[oidx] = acc[fm][fn][r] + bs;
            }
        }
    }
}

// ---- Fallback (verified R2 kernel, diag=0 Wimg + 128-tile Ximg-free path) ----
__global__ __launch_bounds__(256, 2) void fusion_gemm_fb(
    const float* __restrict__ x, const unsigned short* __restrict__ Wimg,
    const float* __restrict__ bsum, float* __restrict__ out) {
    __shared__ __attribute__((aligned(16))) unsigned short Alds[128 * 64];
    __shared__ __attribute__((aligned(16))) unsigned short Blds[2][128 * 64];

    const int tid = threadIdx.x;
    const int bid = blockIdx.x;
    const int xcd = bid & 7;
    const int slot = bid >> 3;
    const int ct = slot & 7;
    const int rhi = slot >> 3;
    const int rtile = rhi * 8 + xcd;
    const int n0 = rtile * 128;
    const int col0 = ct * 128;
    const int i = ct >> 1;

    const int lane = tid & 63;
    const int wid = tid >> 6;
    const int wm = wid >> 1;
    const int wn = wid & 1;

    f32x4 acc[4][4];
    #pragma unroll
    for (int a = 0; a < 4; ++a)
        #pragma unroll
        for (int b2 = 0; b2 < 4; ++b2)
            acc[a][b2] = (f32x4){0.f, 0.f, 0.f, 0.f};

    const int sr = tid >> 1;
    const int sh = tid & 1;
    char* Ab = (char*)Alds;
    const char* WimgB = (const char*)Wimg;

    f32x4 av[8];
    {
        int j0 = (i == 0) ? 1 : 0;
        const float* asrc = x + (size_t)j0 * ((size_t)NN * DD) + (size_t)(n0 + sr) * DD + sh * 32;
        #pragma unroll
        for (int q = 0; q < 8; ++q) av[q] = *(const f32x4*)(asrc + q * 4);
        const char* base = WimgB + (((size_t)(ct * 4 + j0) * 4 + 0) << 14) + wid * 1024 + lane * 16;
        char* lb = (char*)Blds[0] + wid * 1024;
        #pragma unroll
        for (int q = 0; q < 4; ++q) gl2lds16(base + q * 4096, lb + q * 4096);
    }

    for (int t = 0; t < 12; ++t) {
        __syncthreads();
        #pragma unroll
        for (int q = 0; q < 4; ++q) {
            f32x4 v0 = av[2 * q], v1 = av[2 * q + 1];
            u32x4 p;
            p[0] = (u32)f2bf(v0[0]) | ((u32)f2bf(v0[1]) << 16);
            p[1] = (u32)f2bf(v0[2]) | ((u32)f2bf(v0[3]) << 16);
            p[2] = (u32)f2bf(v1[0]) | ((u32)f2bf(v1[1]) << 16);
            p[3] = (u32)f2bf(v1[2]) | ((u32)f2bf(v1[3]) << 16);
            u32 o = (u32)(sr * 128 + sh * 64 + q * 16);
            o ^= (u32)((sr & 7) << 4);
            *(u32x4*)(Ab + o) = p;
        }
        __syncthreads();

        if (t < 11) {
            int tn = t + 1;
            int jjn = tn >> 2;
            int jn = jjn + (jjn >= i);
            int kkn = tn & 3;
            const char* base = WimgB + (((size_t)(ct * 4 + jn) * 4 + kkn) << 14) + wid * 1024 + lane * 16;
            char* lb = (char*)Blds[tn & 1] + wid * 1024;
            #pragma unroll
            for (int q = 0; q < 4; ++q) gl2lds16(base + q * 4096, lb + q * 4096);
            const float* asrc = x + (size_t)jn * ((size_t)NN * DD) + (size_t)(n0 + sr) * DD + kkn * 64 + sh * 32;
            #pragma unroll
            for (int q = 0; q < 8; ++q) av[q] = *(const f32x4*)(asrc + q * 4);
        }

        const char* Bb = (const char*)Blds[t & 1];
        #pragma unroll
        for (int kh = 0; kh < 2; ++kh) {
            s16x8 af[4], bfr[4];
            #pragma unroll
            for (int fm = 0; fm < 4; ++fm) {
                int row = wm * 64 + fm * 16 + (lane & 15);
                u32 o = (u32)(row * 128 + kh * 64 + (lane >> 4) * 16);
                o ^= (u32)((row & 7) << 4);
                af[fm] = *(const s16x8*)(Ab + o);
            }
            #pragma unroll
            for (int fn = 0; fn < 4; ++fn) {
                int col = wn * 64 + fn * 16 + (lane & 15);
                u32 o = (u32)(col * 128 + kh * 64 + (lane >> 4) * 16);
                o ^= (u32)((col & 7) << 4);
                bfr[fn] = *(const s16x8*)(Bb + o);
            }
            #pragma unroll
            for (int fm = 0; fm < 4; ++fm)
                #pragma unroll
                for (int fn = 0; fn < 4; ++fn)
                    acc[fm][fn] = __builtin_amdgcn_mfma_f32_16x16x32_bf16(
                        af[fm], bfr[fn], acc[fm][fn], 0, 0, 0);
        }
    }

    const int r0 = (lane >> 4) * 4;
    const int cl = lane & 15;
    #pragma unroll
    for (int fm = 0; fm < 4; ++fm) {
        #pragma unroll
        for (int fn = 0; fn < 4; ++fn) {
            int col_l = wn * 64 + fn * 16 + cl;
            int cglob = col0 + col_l;
            float bs = bsum[cglob];
            int e = cglob & 255;
            #pragma unroll
            for (int r = 0; r < 4; ++r) {
                int row_l = wm * 64 + fm * 16 + r0 + r;
                int n = n0 + row_l;
                size_t oidx = ((size_t)i * NN + n) * DD + e;
                out[oidx] = acc[fm][fn][r] + x[oidx] + bs;
            }
        }
    }
}

extern "C" void kernel_launch(void* const* d_in, const int* in_sizes, int n_in,
                              void* d_out, int out_size, void* d_ws, size_t ws_size,
                              hipStream_t stream) {
    const float* x = (const float*)d_in[0];
    const float* W = (const float*)d_in[1];
    const float* b = (const float*)d_in[2];
    float* out = (float*)d_out;

    unsigned short* Wimg = (unsigned short*)d_ws;                      // 2 MB
    float* bsum = (float*)((char*)d_ws + ((size_t)2 << 20));           // 4 KB
    const size_t ximg_off = (size_t)4 << 20;
    const size_t need = ximg_off + ((size_t)128 << 20);                // 132 MB

    hipLaunchKernelGGL(prep_b, dim3(4), dim3(256), 0, stream, b, bsum);

    if (ws_size >= need) {
        unsigned short* Ximg = (unsigned short*)((char*)d_ws + ximg_off);  // 128 MB
        hipLaunchKernelGGL(prep_w, dim3(1024), dim3(256), 0, stream, W, Wimg, 1);
        hipLaunchKernelGGL(prep_x, dim3(65536), dim3(256), 0, stream, x, Ximg);
        hipLaunchKernelGGL(fusion_gemm3, dim3(2048), dim3(512), 0, stream, Wimg, Ximg, bsum, out);
    } else {
        hipLaunchKernelGGL(prep_w, dim3(1024), dim3(256), 0, stream, W, Wimg, 0);
        hipLaunchKernelGGL(fusion_gemm_fb, dim3(4096), dim3(256), 0, stream, x, Wimg, bsum, out);
    }
}